// Round 2
// baseline (31233.737 us; speedup 1.0000x reference)
//
#include <hip/hip_runtime.h>

#define B_ 128
#define S_ 1024
#define I_ 512
#define H_ 1024
#define O_ 512
#define KC_ 1536           // I_ + H_
#define R_ (B_*S_)         // 131072 rows
#define P2_WGS 128

typedef __attribute__((ext_vector_type(8))) __bf16 bf16x8;
typedef __attribute__((ext_vector_type(4))) float f32x4;
typedef unsigned short u16;
typedef __attribute__((ext_vector_type(8))) u16 u16x8;
typedef __attribute__((ext_vector_type(4))) float f4v;

__device__ __forceinline__ u16 f2bf(float f) {
  unsigned u = __builtin_bit_cast(unsigned, f);
  u += 0x7fffu + ((u >> 16) & 1u);          // round-to-nearest-even
  return (u16)(u >> 16);
}
__device__ __forceinline__ float bf2f(u16 s) {
  unsigned u = ((unsigned)s) << 16;
  return __builtin_bit_cast(float, u);
}

// ---------- prep kernels ----------

// cast x [B,S,I] fp32 -> Aall[r, 0:I) bf16 (r = b*S + s), Aall row stride KC_
__global__ void k_prep_x(const float* __restrict__ x, u16* __restrict__ Aall) {
  const long n8 = (long)R_ * I_ / 8;
  long stride = (long)gridDim.x * blockDim.x;
  for (long i = (long)blockIdx.x * blockDim.x + threadIdx.x; i < n8; i += stride) {
    long e = i * 8;
    long r = e >> 9;            // / I_
    int  c = (int)(e & (I_ - 1));
    f4v v0 = *(const f4v*)(x + e);
    f4v v1 = *(const f4v*)(x + e + 4);
    u16x8 o;
    o[0]=f2bf(v0[0]); o[1]=f2bf(v0[1]); o[2]=f2bf(v0[2]); o[3]=f2bf(v0[3]);
    o[4]=f2bf(v1[0]); o[5]=f2bf(v1[1]); o[6]=f2bf(v1[2]); o[7]=f2bf(v1[3]);
    *(u16x8*)(Aall + r * KC_ + c) = o;
  }
}

// split/cast W_ih [H,KC] -> Wx [H,I] + Wh [H,H] bf16 ; cast W_io [O,KC] -> Wio bf16
__global__ void k_prep_w(const float* __restrict__ Wih, const float* __restrict__ Wio,
                         u16* __restrict__ Wx, u16* __restrict__ Wh, u16* __restrict__ WioB) {
  const long nA = (long)H_ * KC_ / 8;
  const long nB = (long)O_ * KC_ / 8;
  long stride = (long)gridDim.x * blockDim.x;
  for (long i = (long)blockIdx.x * blockDim.x + threadIdx.x; i < nA + nB; i += stride) {
    if (i < nA) {
      long e = i * 8;
      int n = (int)(e / KC_);
      int k = (int)(e % KC_);
      u16x8 o;
      #pragma unroll
      for (int j = 0; j < 8; ++j) o[j] = f2bf(Wih[e + j]);
      if (k < I_) *(u16x8*)(Wx + (long)n * I_ + k) = o;
      else        *(u16x8*)(Wh + (long)n * H_ + (k - I_)) = o;
    } else {
      long e = (i - nA) * 8;
      u16x8 o;
      #pragma unroll
      for (int j = 0; j < 8; ++j) o[j] = f2bf(Wio[e + j]);
      *(u16x8*)(WioB + e) = o;
    }
  }
}

// hidden0 [B,H] fp32 -> Aall[(b*S+0), I_ + h] bf16 ; zero the barrier counter
__global__ void k_prep_h0(const float* __restrict__ h0, u16* __restrict__ Aall,
                          unsigned* __restrict__ cnt) {
  if (blockIdx.x == 0 && threadIdx.x == 0) *cnt = 0;
  const long n8 = (long)B_ * H_ / 8;
  long stride = (long)gridDim.x * blockDim.x;
  for (long i = (long)blockIdx.x * blockDim.x + threadIdx.x; i < n8; i += stride) {
    long e = i * 8;
    int b = (int)(e >> 10);           // / H_
    int h = (int)(e & (H_ - 1));
    u16x8 o;
    #pragma unroll
    for (int j = 0; j < 8; ++j) o[j] = f2bf(h0[e + j]);
    *(u16x8*)(Aall + ((long)b * S_) * KC_ + I_ + h) = o;
  }
}

// ---------- 64x256-tile bf16 MFMA GEMM:  C[M,N] = A[M,K] @ Bw[N,K]^T ----------
// grid.x = M/64, grid.y = N/256; block = 256 (4 waves 2x2; wave = 32 rows x 128 cols)
template<int KLEN, int LDA, int LDC, bool OUTBF, bool BIAS>
__global__ __launch_bounds__(256) void k_gemm(
    const u16* __restrict__ A, const u16* __restrict__ Bw,
    void* __restrict__ Cp, const float* __restrict__ bias)
{
  int tm = blockIdx.x, tn = blockIdx.y;
  int wave = threadIdx.x >> 6;
  int lane = threadIdx.x & 63;
  int wm = (wave >> 1) * 32;
  int wn = (wave & 1) * 128;
  int l15 = lane & 15, lg = lane >> 4;

  f32x4 acc[2][8] = {};
  const u16* A0 = A  + (long)(tm * 64 + wm + l15) * LDA + lg * 8;
  const u16* A1 = A0 + (long)16 * LDA;
  const u16* Bb = Bw + (long)(tn * 256 + wn + l15) * KLEN + lg * 8;

  #pragma unroll 2
  for (int kk = 0; kk < KLEN; kk += 32) {
    bf16x8 a0 = *(const bf16x8*)(A0 + kk);
    bf16x8 a1 = *(const bf16x8*)(A1 + kk);
    #pragma unroll
    for (int j = 0; j < 8; ++j) {
      bf16x8 b = *(const bf16x8*)(Bb + (long)j * 16 * KLEN + kk);
      acc[0][j] = __builtin_amdgcn_mfma_f32_16x16x32_bf16(a0, b, acc[0][j], 0, 0, 0);
      acc[1][j] = __builtin_amdgcn_mfma_f32_16x16x32_bf16(a1, b, acc[1][j], 0, 0, 0);
    }
  }

  #pragma unroll
  for (int i = 0; i < 2; ++i) {
    #pragma unroll
    for (int j = 0; j < 8; ++j) {
      int col = tn * 256 + wn + j * 16 + l15;
      float bb = BIAS ? bias[col] : 0.0f;
      #pragma unroll
      for (int r = 0; r < 4; ++r) {
        int row = tm * 64 + wm + i * 16 + lg * 4 + r;
        float v = acc[i][j][r] + bb;
        if (OUTBF) ((u16*)Cp)[(long)row * LDC + col] = f2bf(v);
        else       ((float*)Cp)[(long)row * LDC + col] = v;
      }
    }
  }
}

// ---------- persistent recurrence ----------
// 128 wgs: wg = rg*16 + ct ; ct: 64-col tile of H, rg: 16-row tile of B.
// Wh slice [64 cols][1024 k] staged once in 128KB LDS (XOR-swizzled).
// Per step t: h_{t+1} = tanh(XW[:,t,:] + h_t @ Wh^T + b_ih); device barrier.
__global__ __launch_bounds__(256) void k_rnn(
    u16* __restrict__ Aall, const u16* __restrict__ Wh,
    const u16* __restrict__ XW, const float* __restrict__ b_ih,
    float* __restrict__ hidF, unsigned* __restrict__ cnt)
{
  extern __shared__ char smem[];     // 131072 bytes
  int wg = blockIdx.x;
  int ct = wg & 15;                  // col tile (64 cols)
  int rg = wg >> 4;                  // row group (16 rows)
  int tid = threadIdx.x;
  int wave = tid >> 6, lane = tid & 63;
  int l15 = lane & 15, lg = lane >> 4;

  // stage Wh slice: cols ct*64..+63, all k. swizzle byte ^= (col&7)<<4
  #pragma unroll 4
  for (int i = 0; i < 32; ++i) {
    int e = (i * 256 + tid) * 8;
    int c = e >> 10, k = e & 1023;
    u16x8 v = *(const u16x8*)(Wh + (long)(ct * 64 + c) * H_ + k);
    int byt = (c << 11) + (k << 1);
    byt ^= (c & 7) << 4;
    *(u16x8*)(smem + byt) = v;
  }
  __syncthreads();

  // this lane's fixed output column and LDS read address pieces
  int cc  = (wave << 4) + l15;           // col within slice (wave owns 16 cols)
  int col = (ct << 6) + cc;              // global H col
  float bias = b_ih[col];
  // epilogue rows: b = rg*16 + lg*4 + r   (C/D: col=lane&15, row=(lane>>4)*4+r)
  const u16* XWp[4];
  u16* Wr[4];
  float* Hf[4];
  #pragma unroll
  for (int r = 0; r < 4; ++r) {
    int b = (rg << 4) + (lg << 2) + r;
    XWp[r] = XW + ((long)b * S_) * H_ + col;
    Wr[r]  = Aall + ((long)b * S_) * KC_ + I_ + col;
    Hf[r]  = hidF + (long)b * H_ + col;
  }
  // A-frag row pointer: row = rg*16 + l15
  const u16* Arow = Aall + ((long)((rg << 4) + l15) * S_) * KC_ + I_ + (lg << 3);

  for (int t = 0; t < S_; ++t) {
    // prefetch XW values for this step (independent of h)
    float xwv[4];
    #pragma unroll
    for (int r = 0; r < 4; ++r) xwv[r] = bf2f(XWp[r][(long)t * H_]);

    const u16* Ap = Arow + (long)t * KC_;
    f32x4 acc0 = {}, acc1 = {};
    #pragma unroll 8
    for (int kk = 0; kk < H_; kk += 64) {
      bf16x8 a0 = *(const bf16x8*)(Ap + kk);
      bf16x8 a1 = *(const bf16x8*)(Ap + kk + 32);
      int k0 = kk + (lg << 3);
      int b0 = ((cc << 11) + (k0 << 1)) ^ ((cc & 7) << 4);
      int b1 = ((cc << 11) + ((k0 + 32) << 1)) ^ ((cc & 7) << 4);
      bf16x8 bA = *(const bf16x8*)(smem + b0);
      bf16x8 bB = *(const bf16x8*)(smem + b1);
      acc0 = __builtin_amdgcn_mfma_f32_16x16x32_bf16(a0, bA, acc0, 0, 0, 0);
      acc1 = __builtin_amdgcn_mfma_f32_16x16x32_bf16(a1, bB, acc1, 0, 0, 0);
    }

    #pragma unroll
    for (int r = 0; r < 4; ++r) {
      float v = acc0[r] + acc1[r] + xwv[r] + bias;
      float h = tanhf(v);
      if (t + 1 < S_) Wr[r][(long)(t + 1) * KC_] = f2bf(h);
      else            Hf[r][0] = h;
    }

    // device barrier: release writes, arrive, spin, acquire
    __threadfence();
    __syncthreads();
    if (tid == 0) {
      __hip_atomic_fetch_add(cnt, 1u, __ATOMIC_RELEASE, __HIP_MEMORY_SCOPE_AGENT);
      unsigned target = (unsigned)P2_WGS * (unsigned)(t + 1);
      while (__hip_atomic_load(cnt, __ATOMIC_ACQUIRE, __HIP_MEMORY_SCOPE_AGENT) < target) {
        __builtin_amdgcn_s_sleep(1);
      }
    }
    __syncthreads();
    __threadfence();
  }
}

// ---------- launch ----------
extern "C" void kernel_launch(void* const* d_in, const int* in_sizes, int n_in,
                              void* d_out, int out_size, void* d_ws, size_t ws_size,
                              hipStream_t stream) {
  const float* x    = (const float*)d_in[0];
  const float* h0   = (const float*)d_in[1];
  const float* Wih  = (const float*)d_in[2];
  const float* b_ih = (const float*)d_in[3];
  const float* Wio  = (const float*)d_in[4];
  const float* b_io = (const float*)d_in[5];
  float* out = (float*)d_out;

  char* ws = (char*)d_ws;
  u16* Aall = (u16*)(ws);                       // 402,653,184 B
  u16* XW   = (u16*)(ws + 402653184L);          // 268,435,456 B
  u16* Wx   = (u16*)(ws + 671088640L);          //   1,048,576 B
  u16* Wh   = (u16*)(ws + 672137216L);          //   2,097,152 B
  u16* WioB = (u16*)(ws + 674234368L);          //   1,572,864 B
  unsigned* cnt = (unsigned*)(ws + 675807232L); //           4 B

  // prep
  k_prep_x<<<2048, 256, 0, stream>>>(x, Aall);
  k_prep_w<<<512, 256, 0, stream>>>(Wih, Wio, Wx, Wh, WioB);
  k_prep_h0<<<64, 256, 0, stream>>>(h0, Aall, cnt);

  // phase 1: XW = x @ Wih_x^T   (M=R_, N=H_=1024, K=I_)
  k_gemm<I_, KC_, H_, true, false>
      <<<dim3(R_/64, H_/256), 256, 0, stream>>>(Aall, Wx, (void*)XW, nullptr);

  // phase 2: persistent recurrence (128 wgs, 128KB dynamic LDS each)
  k_rnn<<<P2_WGS, 256, 131072, stream>>>(Aall, Wh, XW, b_ih, out + (long)R_ * O_, cnt);

  // phase 3: outputs = Aall @ Wio^T + b_io  (M=R_, N=O_=512, K=KC_)
  k_gemm<KC_, KC_, O_, false, true>
      <<<dim3(R_/64, O_/256), 256, 0, stream>>>(Aall, WioB, d_out, b_io);
}

// Round 3
// 11999.526 us; speedup vs baseline: 2.6029x; 2.6029x over previous
//
#include <hip/hip_runtime.h>

#define B_ 128
#define S_ 1024
#define I_ 512
#define H_ 1024
#define O_ 512
#define KC_ 1536           // I_ + H_
#define R_ (B_*S_)         // 131072 rows
#define P2_WGS 128

typedef __attribute__((ext_vector_type(8))) __bf16 bf16x8;
typedef __attribute__((ext_vector_type(4))) float f32x4;
typedef unsigned short u16;
typedef unsigned long long u64;
typedef __attribute__((ext_vector_type(8))) u16 u16x8;
typedef __attribute__((ext_vector_type(4))) float f4v;
typedef __attribute__((ext_vector_type(2))) u64 u64x2;

__device__ __forceinline__ u16 f2bf(float f) {
  unsigned u = __builtin_bit_cast(unsigned, f);
  u += 0x7fffu + ((u >> 16) & 1u);          // round-to-nearest-even
  return (u16)(u >> 16);
}
__device__ __forceinline__ float bf2f(u16 s) {
  unsigned u = ((unsigned)s) << 16;
  return __builtin_bit_cast(float, u);
}

// ---------- prep kernels ----------

__global__ void k_prep_x(const float* __restrict__ x, u16* __restrict__ Aall) {
  const long n8 = (long)R_ * I_ / 8;
  long stride = (long)gridDim.x * blockDim.x;
  for (long i = (long)blockIdx.x * blockDim.x + threadIdx.x; i < n8; i += stride) {
    long e = i * 8;
    long r = e >> 9;            // / I_
    int  c = (int)(e & (I_ - 1));
    f4v v0 = *(const f4v*)(x + e);
    f4v v1 = *(const f4v*)(x + e + 4);
    u16x8 o;
    o[0]=f2bf(v0[0]); o[1]=f2bf(v0[1]); o[2]=f2bf(v0[2]); o[3]=f2bf(v0[3]);
    o[4]=f2bf(v1[0]); o[5]=f2bf(v1[1]); o[6]=f2bf(v1[2]); o[7]=f2bf(v1[3]);
    *(u16x8*)(Aall + r * KC_ + c) = o;
  }
}

__global__ void k_prep_w(const float* __restrict__ Wih, const float* __restrict__ Wio,
                         u16* __restrict__ Wx, u16* __restrict__ Wh, u16* __restrict__ WioB) {
  const long nA = (long)H_ * KC_ / 8;
  const long nB = (long)O_ * KC_ / 8;
  long stride = (long)gridDim.x * blockDim.x;
  for (long i = (long)blockIdx.x * blockDim.x + threadIdx.x; i < nA + nB; i += stride) {
    if (i < nA) {
      long e = i * 8;
      int n = (int)(e / KC_);
      int k = (int)(e % KC_);
      u16x8 o;
      #pragma unroll
      for (int j = 0; j < 8; ++j) o[j] = f2bf(Wih[e + j]);
      if (k < I_) *(u16x8*)(Wx + (long)n * I_ + k) = o;
      else        *(u16x8*)(Wh + (long)n * H_ + (k - I_)) = o;
    } else {
      long e = (i - nA) * 8;
      u16x8 o;
      #pragma unroll
      for (int j = 0; j < 8; ++j) o[j] = f2bf(Wio[e + j]);
      *(u16x8*)(WioB + e) = o;
    }
  }
}

// hidden0 -> Aall t=0 slot ; zero the 256 flag words
__global__ void k_prep_h0(const float* __restrict__ h0, u16* __restrict__ Aall,
                          unsigned* __restrict__ flags) {
  if (blockIdx.x == 0 && threadIdx.x < 256) flags[threadIdx.x] = 0;
  const long n8 = (long)B_ * H_ / 8;
  long stride = (long)gridDim.x * blockDim.x;
  for (long i = (long)blockIdx.x * blockDim.x + threadIdx.x; i < n8; i += stride) {
    long e = i * 8;
    int b = (int)(e >> 10);           // / H_
    int h = (int)(e & (H_ - 1));
    u16x8 o;
    #pragma unroll
    for (int j = 0; j < 8; ++j) o[j] = f2bf(h0[e + j]);
    *(u16x8*)(Aall + ((long)b * S_) * KC_ + I_ + h) = o;
  }
}

// ---------- 64x256-tile bf16 MFMA GEMM:  C[M,N] = A[M,K] @ Bw[N,K]^T ----------
template<int KLEN, int LDA, int LDC, bool OUTBF, bool BIAS>
__global__ __launch_bounds__(256) void k_gemm(
    const u16* __restrict__ A, const u16* __restrict__ Bw,
    void* __restrict__ Cp, const float* __restrict__ bias)
{
  int tm = blockIdx.x, tn = blockIdx.y;
  int wave = threadIdx.x >> 6;
  int lane = threadIdx.x & 63;
  int wm = (wave >> 1) * 32;
  int wn = (wave & 1) * 128;
  int l15 = lane & 15, lg = lane >> 4;

  f32x4 acc[2][8] = {};
  const u16* A0 = A  + (long)(tm * 64 + wm + l15) * LDA + lg * 8;
  const u16* A1 = A0 + (long)16 * LDA;
  const u16* Bb = Bw + (long)(tn * 256 + wn + l15) * KLEN + lg * 8;

  #pragma unroll 2
  for (int kk = 0; kk < KLEN; kk += 32) {
    bf16x8 a0 = *(const bf16x8*)(A0 + kk);
    bf16x8 a1 = *(const bf16x8*)(A1 + kk);
    #pragma unroll
    for (int j = 0; j < 8; ++j) {
      bf16x8 b = *(const bf16x8*)(Bb + (long)j * 16 * KLEN + kk);
      acc[0][j] = __builtin_amdgcn_mfma_f32_16x16x32_bf16(a0, b, acc[0][j], 0, 0, 0);
      acc[1][j] = __builtin_amdgcn_mfma_f32_16x16x32_bf16(a1, b, acc[1][j], 0, 0, 0);
    }
  }

  #pragma unroll
  for (int i = 0; i < 2; ++i) {
    #pragma unroll
    for (int j = 0; j < 8; ++j) {
      int col = tn * 256 + wn + j * 16 + l15;
      float bb = BIAS ? bias[col] : 0.0f;
      #pragma unroll
      for (int r = 0; r < 4; ++r) {
        int row = tm * 64 + wm + i * 16 + lg * 4 + r;
        float v = acc[i][j][r] + bb;
        if (OUTBF) ((u16*)Cp)[(long)row * LDC + col] = f2bf(v);
        else       ((float*)Cp)[(long)row * LDC + col] = v;
      }
    }
  }
}

// ---------- persistent recurrence, per-row-group barrier, sc1 data exchange ----------
// 128 wgs: wg = rg*16 + ct. Group rg = 16 wgs exchanging h rows [rg*16, rg*16+16).
// Wh slice [64 cols][1024 k] staged once in 128KB LDS (XOR-swizzled).
// Protocol per step t:
//   poll (relaxed sc1 loads) until all 16 group flags >= t   [h_t published]
//   A-fragments of h_t via relaxed agent (sc1) 8B loads -> MFMA with LDS Wh
//   h_{t+1} = tanh(acc + XW_t + bias): publish via relaxed agent (sc1) 2B stores
//   __syncthreads (drains all waves' stores) ; tid0: flag = t+1 (relaxed sc1)
// No release/acquire fences => no buffer_wbl2 / buffer_inv in the loop.
__global__ __launch_bounds__(256) void k_rnn(
    u16* __restrict__ Aall, const u16* __restrict__ Wh,
    const u16* __restrict__ XW, const float* __restrict__ b_ih,
    float* __restrict__ hidF, unsigned* __restrict__ flags)
{
  extern __shared__ char smem[];     // 131072 bytes
  int wg = blockIdx.x;
  int ct = wg & 15;                  // col tile (64 cols)
  int rg = wg >> 4;                  // row group (16 rows)
  int tid = threadIdx.x;
  int wave = tid >> 6, lane = tid & 63;
  int l15 = lane & 15, lg = lane >> 4;

  // stage Wh slice: cols ct*64..+63, all k. swizzle byte ^= (col&7)<<4
  #pragma unroll 4
  for (int i = 0; i < 32; ++i) {
    int e = (i * 256 + tid) * 8;
    int c = e >> 10, k = e & 1023;
    u16x8 v = *(const u16x8*)(Wh + (long)(ct * 64 + c) * H_ + k);
    int byt = (c << 11) + (k << 1);
    byt ^= (c & 7) << 4;
    *(u16x8*)(smem + byt) = v;
  }
  __syncthreads();

  int cc  = (wave << 4) + l15;           // col within slice (wave owns 16 cols)
  int col = (ct << 6) + cc;              // global H col
  float bias = b_ih[col];
  const u16* XWp[4];
  u16* Wr[4];
  float* Hf[4];
  #pragma unroll
  for (int r = 0; r < 4; ++r) {
    int b = (rg << 4) + (lg << 2) + r;
    XWp[r] = XW + ((long)b * S_) * H_ + col;
    Wr[r]  = Aall + ((long)b * S_) * KC_ + I_ + col;
    Hf[r]  = hidF + (long)b * H_ + col;
  }
  // A-frag row pointer: row = rg*16 + l15, k base lg*8
  const u16* Arow = Aall + ((long)((rg << 4) + l15) * S_) * KC_ + I_ + (lg << 3);

  unsigned* myflag = flags + rg * 32 + ct;
  const unsigned* pollp = flags + rg * 32 + l15;

  // XW software pipeline: load step-0 value now
  float xw_cur[4];
  #pragma unroll
  for (int r = 0; r < 4; ++r) xw_cur[r] = bf2f(XWp[r][0]);

  for (int t = 0; t < S_; ++t) {
    // ---- group barrier: wait for h_t from all 16 col-tile wgs ----
    if (t > 0) {
      while (true) {
        unsigned v = __hip_atomic_load(pollp, __ATOMIC_RELAXED, __HIP_MEMORY_SCOPE_AGENT);
        if (__all((int)(v >= (unsigned)t))) break;
        __builtin_amdgcn_s_sleep(1);
      }
      asm volatile("" ::: "memory");   // compiler barrier: keep loads below the poll
    }

    // prefetch next step's XW contribution (normal cached loads, hidden under MFMA)
    float xw_nxt[4] = {0.f, 0.f, 0.f, 0.f};
    if (t + 1 < S_) {
      #pragma unroll
      for (int r = 0; r < 4; ++r) xw_nxt[r] = bf2f(XWp[r][(long)(t + 1) * H_]);
    }

    // ---- h_t @ Wh^T : A-fragments via device-coherent (sc1) 8B loads ----
    const u16* Ap = Arow + (long)t * KC_;
    f32x4 acc0 = {}, acc1 = {};
    #pragma unroll 8
    for (int kk = 0; kk < H_; kk += 64) {
      u64 lo0 = __hip_atomic_load((const u64*)(Ap + kk),      __ATOMIC_RELAXED, __HIP_MEMORY_SCOPE_AGENT);
      u64 hi0 = __hip_atomic_load((const u64*)(Ap + kk + 4),  __ATOMIC_RELAXED, __HIP_MEMORY_SCOPE_AGENT);
      u64 lo1 = __hip_atomic_load((const u64*)(Ap + kk + 32), __ATOMIC_RELAXED, __HIP_MEMORY_SCOPE_AGENT);
      u64 hi1 = __hip_atomic_load((const u64*)(Ap + kk + 36), __ATOMIC_RELAXED, __HIP_MEMORY_SCOPE_AGENT);
      u64x2 p0; p0[0] = lo0; p0[1] = hi0;
      u64x2 p1; p1[0] = lo1; p1[1] = hi1;
      bf16x8 a0 = __builtin_bit_cast(bf16x8, p0);
      bf16x8 a1 = __builtin_bit_cast(bf16x8, p1);
      int k0 = kk + (lg << 3);
      int b0 = ((cc << 11) + (k0 << 1)) ^ ((cc & 7) << 4);
      int b1 = ((cc << 11) + ((k0 + 32) << 1)) ^ ((cc & 7) << 4);
      bf16x8 bA = *(const bf16x8*)(smem + b0);
      bf16x8 bB = *(const bf16x8*)(smem + b1);
      acc0 = __builtin_amdgcn_mfma_f32_16x16x32_bf16(a0, bA, acc0, 0, 0, 0);
      acc1 = __builtin_amdgcn_mfma_f32_16x16x32_bf16(a1, bB, acc1, 0, 0, 0);
    }

    // ---- epilogue: tanh + publish h_{t+1} (sc1 2B stores) ----
    #pragma unroll
    for (int r = 0; r < 4; ++r) {
      float v = acc0[r] + acc1[r] + xw_cur[r] + bias;
      float h = tanhf(v);
      if (t + 1 < S_) {
        __hip_atomic_store(Wr[r] + (long)(t + 1) * KC_, f2bf(h),
                           __ATOMIC_RELAXED, __HIP_MEMORY_SCOPE_AGENT);
      } else {
        Hf[r][0] = h;                 // final hidden, fp32 (kernel-end flush)
      }
    }
    #pragma unroll
    for (int r = 0; r < 4; ++r) xw_cur[r] = xw_nxt[r];

    // all waves' sc1 stores drain at the pre-barrier vmcnt(0); then signal
    __syncthreads();
    if (tid == 0)
      __hip_atomic_store(myflag, (unsigned)(t + 1),
                         __ATOMIC_RELAXED, __HIP_MEMORY_SCOPE_AGENT);
  }
}

// ---------- launch ----------
extern "C" void kernel_launch(void* const* d_in, const int* in_sizes, int n_in,
                              void* d_out, int out_size, void* d_ws, size_t ws_size,
                              hipStream_t stream) {
  const float* x    = (const float*)d_in[0];
  const float* h0   = (const float*)d_in[1];
  const float* Wih  = (const float*)d_in[2];
  const float* b_ih = (const float*)d_in[3];
  const float* Wio  = (const float*)d_in[4];
  const float* b_io = (const float*)d_in[5];
  float* out = (float*)d_out;

  char* ws = (char*)d_ws;
  u16* Aall = (u16*)(ws);                        // 402,653,184 B
  u16* XW   = (u16*)(ws + 402653184L);           // 268,435,456 B
  u16* Wx   = (u16*)(ws + 671088640L);           //   1,048,576 B
  u16* Wh   = (u16*)(ws + 672137216L);           //   2,097,152 B
  u16* WioB = (u16*)(ws + 674234368L);           //   1,572,864 B
  unsigned* flags = (unsigned*)(ws + 675807232L);//       1,024 B (256 u32)

  // prep
  k_prep_x<<<2048, 256, 0, stream>>>(x, Aall);
  k_prep_w<<<512, 256, 0, stream>>>(Wih, Wio, Wx, Wh, WioB);
  k_prep_h0<<<64, 256, 0, stream>>>(h0, Aall, flags);

  // phase 1: XW = x @ Wih_x^T   (M=R_, N=H_=1024, K=I_)
  k_gemm<I_, KC_, H_, true, false>
      <<<dim3(R_/64, H_/256), 256, 0, stream>>>(Aall, Wx, (void*)XW, nullptr);

  // phase 2: persistent recurrence (128 wgs, 128KB dynamic LDS each)
  k_rnn<<<P2_WGS, 256, 131072, stream>>>(Aall, Wh, XW, b_ih, out + (long)R_ * O_, flags);

  // phase 3: outputs = Aall @ Wio^T + b_io  (M=R_, N=O_=512, K=KC_)
  k_gemm<KC_, KC_, O_, false, true>
      <<<dim3(R_/64, O_/256), 256, 0, stream>>>(Aall, WioB, d_out, b_io);
}

// Round 5
// 9060.259 us; speedup vs baseline: 3.4473x; 1.3244x over previous
//
#include <hip/hip_runtime.h>

#define B_ 128
#define S_ 1024
#define I_ 512
#define H_ 1024
#define O_ 512
#define KC_ 1536           // I_ + H_
#define R_ (B_*S_)         // 131072 rows

typedef __attribute__((ext_vector_type(8))) __bf16 bf16x8;
typedef __attribute__((ext_vector_type(4))) float f32x4;
typedef unsigned short u16;
typedef unsigned long long u64;
typedef __attribute__((ext_vector_type(8))) u16 u16x8;
typedef __attribute__((ext_vector_type(4))) float f4v;

__device__ __forceinline__ u16 f2bf(float f) {
  unsigned u = __builtin_bit_cast(unsigned, f);
  u += 0x7fffu + ((u >> 16) & 1u);          // round-to-nearest-even
  return (u16)(u >> 16);
}
__device__ __forceinline__ float bf2f(u16 s) {
  unsigned u = ((unsigned)s) << 16;
  return __builtin_bit_cast(float, u);
}

// device-coherent 16B load (reads at the coherence point): cross-wg h exchange
__device__ __forceinline__ u16x8 gload16_cc(const u16* p) {
  u16x8 r;
  asm volatile("global_load_dwordx4 %0, %1, off sc0 sc1" : "=v"(r) : "v"(p));
  return r;
}

// ---------- prep kernels ----------

__global__ void k_prep_x(const float* __restrict__ x, u16* __restrict__ Aall) {
  const long n8 = (long)R_ * I_ / 8;
  long stride = (long)gridDim.x * blockDim.x;
  for (long i = (long)blockIdx.x * blockDim.x + threadIdx.x; i < n8; i += stride) {
    long e = i * 8;
    long r = e >> 9;
    int  c = (int)(e & (I_ - 1));
    f4v v0 = *(const f4v*)(x + e);
    f4v v1 = *(const f4v*)(x + e + 4);
    u16x8 o;
    o[0]=f2bf(v0[0]); o[1]=f2bf(v0[1]); o[2]=f2bf(v0[2]); o[3]=f2bf(v0[3]);
    o[4]=f2bf(v1[0]); o[5]=f2bf(v1[1]); o[6]=f2bf(v1[2]); o[7]=f2bf(v1[3]);
    *(u16x8*)(Aall + r * KC_ + c) = o;
  }
}

__global__ void k_prep_w(const float* __restrict__ Wih, const float* __restrict__ Wio,
                         u16* __restrict__ Wx, u16* __restrict__ Wh, u16* __restrict__ WioB) {
  const long nA = (long)H_ * KC_ / 8;
  const long nB = (long)O_ * KC_ / 8;
  long stride = (long)gridDim.x * blockDim.x;
  for (long i = (long)blockIdx.x * blockDim.x + threadIdx.x; i < nA + nB; i += stride) {
    if (i < nA) {
      long e = i * 8;
      int n = (int)(e / KC_);
      int k = (int)(e % KC_);
      u16x8 o;
      #pragma unroll
      for (int j = 0; j < 8; ++j) o[j] = f2bf(Wih[e + j]);
      if (k < I_) *(u16x8*)(Wx + (long)n * I_ + k) = o;
      else        *(u16x8*)(Wh + (long)n * H_ + (k - I_)) = o;
    } else {
      long e = (i - nA) * 8;
      u16x8 o;
      #pragma unroll
      for (int j = 0; j < 8; ++j) o[j] = f2bf(Wio[e + j]);
      *(u16x8*)(WioB + e) = o;
    }
  }
}

// hidden0 -> Aall t=0 slot ; zero the 512 flag words
__global__ void k_prep_h0(const float* __restrict__ h0, u16* __restrict__ Aall,
                          unsigned* __restrict__ flags) {
  if (blockIdx.x < 2) flags[blockIdx.x * 256 + threadIdx.x] = 0;
  const long n8 = (long)B_ * H_ / 8;
  long stride = (long)gridDim.x * blockDim.x;
  for (long i = (long)blockIdx.x * blockDim.x + threadIdx.x; i < n8; i += stride) {
    long e = i * 8;
    int b = (int)(e >> 10);
    int h = (int)(e & (H_ - 1));
    u16x8 o;
    #pragma unroll
    for (int j = 0; j < 8; ++j) o[j] = f2bf(h0[e + j]);
    *(u16x8*)(Aall + ((long)b * S_) * KC_ + I_ + h) = o;
  }
}

// ---------- 64x256-tile bf16 MFMA GEMM:  C[M,N] = A[M,K] @ Bw[N,K]^T ----------
template<int KLEN, int LDA, int LDC, bool OUTBF, bool BIAS>
__global__ __launch_bounds__(256) void k_gemm(
    const u16* __restrict__ A, const u16* __restrict__ Bw,
    void* __restrict__ Cp, const float* __restrict__ bias)
{
  int tm = blockIdx.x, tn = blockIdx.y;
  int wave = threadIdx.x >> 6;
  int lane = threadIdx.x & 63;
  int wm = (wave >> 1) * 32;
  int wn = (wave & 1) * 128;
  int l15 = lane & 15, lg = lane >> 4;

  f32x4 acc[2][8] = {};
  const u16* A0 = A  + (long)(tm * 64 + wm + l15) * LDA + lg * 8;
  const u16* A1 = A0 + (long)16 * LDA;
  const u16* Bb = Bw + (long)(tn * 256 + wn + l15) * KLEN + lg * 8;

  #pragma unroll 2
  for (int kk = 0; kk < KLEN; kk += 32) {
    bf16x8 a0 = *(const bf16x8*)(A0 + kk);
    bf16x8 a1 = *(const bf16x8*)(A1 + kk);
    #pragma unroll
    for (int j = 0; j < 8; ++j) {
      bf16x8 b = *(const bf16x8*)(Bb + (long)j * 16 * KLEN + kk);
      acc[0][j] = __builtin_amdgcn_mfma_f32_16x16x32_bf16(a0, b, acc[0][j], 0, 0, 0);
      acc[1][j] = __builtin_amdgcn_mfma_f32_16x16x32_bf16(a1, b, acc[1][j], 0, 0, 0);
    }
  }

  #pragma unroll
  for (int i = 0; i < 2; ++i) {
    #pragma unroll
    for (int j = 0; j < 8; ++j) {
      int col = tn * 256 + wn + j * 16 + l15;
      float bb = BIAS ? bias[col] : 0.0f;
      #pragma unroll
      for (int r = 0; r < 4; ++r) {
        int row = tm * 64 + wm + i * 16 + lg * 4 + r;
        float v = acc[i][j][r] + bb;
        if (OUTBF) ((u16*)Cp)[(long)row * LDC + col] = f2bf(v);
        else       ((float*)Cp)[(long)row * LDC + col] = v;
      }
    }
  }
}

// ---------- persistent recurrence: Wh in VGPRs, h broadcast via LDS ----------
// 64 wgs: q = p*16 + ct. ct: 64-col tile (4 waves x 16 cols). p: chain pair
// {2p, 2p+1}, each chain = 16 batch rows. Per wave: B-frags bf[32] (128 VGPR)
// held across the whole kernel. Per round t, per chain:
//   poll 64 wave-flags >= t -> coop-load h_t (8x16B sc0sc1/thread) -> LDS
//   (fragment-order layout) -> 32 ds_read_b128 + 32 MFMA -> tanh ->
//   publish h_{t+1} (relaxed-agent 2B stores) -> vmcnt(0) -> flag=t+1.
// Chain 1's L3 latency hides under chain 0's LDS writes; sync RT hides under
// the other chain's compute. No fences => no L2 writeback/invalidate ever.
__global__ __launch_bounds__(256, 1) void k_rnn(
    u16* __restrict__ Aall, const u16* __restrict__ Wh,
    const u16* __restrict__ XW, const float* __restrict__ b_ih,
    float* __restrict__ hidF, unsigned* __restrict__ flags)
{
  __shared__ u16 hbuf[2][16384];     // [chain][(chunk*16+row)*8] = 2 x 32KB
  int q = blockIdx.x;
  int ct = q & 15, p = q >> 4;
  int tid = threadIdx.x;
  int w = tid >> 6, lane = tid & 63;
  int l15 = lane & 15, lg = lane >> 4;
  int col = (ct << 6) + (w << 4) + l15;

  // --- B-fragments: Wh[col][32m + lg*8 ..+8), m=0..31 -> 128 VGPRs ---
  bf16x8 bf[32];
  #pragma unroll
  for (int m = 0; m < 32; ++m)
    bf[m] = *(const bf16x8*)(Wh + (long)col * H_ + 32 * m + (lg << 3));

  float bias = b_ih[col];
  int rbase[2] = { (2 * p) * 16, (2 * p + 1) * 16 };

  // coop-load source: row = rbase[j]+(tid&15), k-chunk base (tid>>4)*8
  const u16* src[2];
  // publish / XW / final-hidden pointers for rows rbase[j]+lg*4+r
  u16* pub[2][4];
  const u16* xwp[2][4];
  float* hf[2][4];
  #pragma unroll
  for (int j = 0; j < 2; ++j) {
    src[j] = Aall + ((long)(rbase[j] + (tid & 15)) * S_) * KC_ + I_ + ((tid >> 4) << 3);
    #pragma unroll
    for (int r = 0; r < 4; ++r) {
      int b = rbase[j] + (lg << 2) + r;
      pub[j][r] = Aall + ((long)b * S_) * KC_ + I_ + col;
      xwp[j][r] = XW + ((long)b * S_) * H_ + col;
      hf[j][r]  = hidF + (long)b * H_ + col;
    }
  }
  unsigned* myflag[2];
  const unsigned* pollp[2];
  #pragma unroll
  for (int j = 0; j < 2; ++j) {
    myflag[j] = flags + (2 * p + j) * 64 + (ct << 2) + w;
    pollp[j]  = flags + (2 * p + j) * 64 + lane;
  }

  // prologue: XW contribution for step 0
  float xw_cur[2][4];
  #pragma unroll
  for (int j = 0; j < 2; ++j)
    #pragma unroll
    for (int r = 0; r < 4; ++r) xw_cur[j][r] = bf2f(xwp[j][r][0]);

  for (int t = 0; t < S_; ++t) {
    long tKC = (long)t * KC_;
    // ---- polls: both chains' h_t published? ----
    if (t) {
      #pragma unroll
      for (int j = 0; j < 2; ++j) {
        while (true) {
          unsigned v = __hip_atomic_load(pollp[j], __ATOMIC_RELAXED, __HIP_MEMORY_SCOPE_AGENT);
          if (__all((int)(v >= (unsigned)t))) break;
          __builtin_amdgcn_s_sleep(1);
        }
      }
      asm volatile("" ::: "memory");
      __builtin_amdgcn_sched_barrier(0);
    }

    // ---- issue all coherent h loads (8 per chain per thread) ----
    u16x8 ar[2][8];
    #pragma unroll
    for (int j = 0; j < 2; ++j)
      #pragma unroll
      for (int jj = 0; jj < 8; ++jj)
        ar[j][jj] = gload16_cc(src[j] + tKC + 128 * jj);

    // ---- issue XW prefetch for step t+1 (normal cached, 4 per chain) ----
    long tn = (t + 1 < S_) ? (long)(t + 1) : (long)t;
    unsigned xwraw[2][4];
    #pragma unroll
    for (int j = 0; j < 2; ++j)
      #pragma unroll
      for (int r = 0; r < 4; ++r)
        asm volatile("global_load_ushort %0, %1, off"
                     : "=v"(xwraw[j][r]) : "v"(xwp[j][r] + tn * H_));

    // ---- LDS stage chain 0 (A-chain-0 loads done; rest still in flight) ----
    asm volatile("s_waitcnt vmcnt(16)" ::: "memory");
    __builtin_amdgcn_sched_barrier(0);
    #pragma unroll
    for (int jj = 0; jj < 8; ++jj)
      *(u16x8*)&hbuf[0][(((tid >> 4) + 16 * jj) * 16 + (tid & 15)) * 8] = ar[0][jj];

    // ---- LDS stage chain 1 ----
    asm volatile("s_waitcnt vmcnt(8)" ::: "memory");
    __builtin_amdgcn_sched_barrier(0);
    #pragma unroll
    for (int jj = 0; jj < 8; ++jj)
      *(u16x8*)&hbuf[1][(((tid >> 4) + 16 * jj) * 16 + (tid & 15)) * 8] = ar[1][jj];

    __syncthreads();

    // ---- compute + publish per chain ----
    #pragma unroll
    for (int j = 0; j < 2; ++j) {
      f32x4 acc0 = {}, acc1 = {};
      #pragma unroll
      for (int m = 0; m < 32; m += 2) {
        bf16x8 a0 = *(const bf16x8*)&hbuf[j][((4 * m + lg) * 16 + l15) * 8];
        bf16x8 a1 = *(const bf16x8*)&hbuf[j][((4 * (m + 1) + lg) * 16 + l15) * 8];
        acc0 = __builtin_amdgcn_mfma_f32_16x16x32_bf16(a0, bf[m],     acc0, 0, 0, 0);
        acc1 = __builtin_amdgcn_mfma_f32_16x16x32_bf16(a1, bf[m + 1], acc1, 0, 0, 0);
      }
      #pragma unroll
      for (int r = 0; r < 4; ++r) {
        float v = acc0[r] + acc1[r] + xw_cur[j][r] + bias;
        float h = tanhf(v);
        if (t + 1 < S_)
          __hip_atomic_store(pub[j][r] + (long)(t + 1) * KC_, f2bf(h),
                             __ATOMIC_RELAXED, __HIP_MEMORY_SCOPE_AGENT);
        else
          hf[j][r][0] = h;
      }
      // publishes (and any strays) drained, then signal
      asm volatile("s_waitcnt vmcnt(0)" ::: "memory");
      __builtin_amdgcn_sched_barrier(0);
      if (lane == 0)
        __hip_atomic_store(myflag[j], (unsigned)(t + 1),
                           __ATOMIC_RELAXED, __HIP_MEMORY_SCOPE_AGENT);
      // XW raw bits are valid after the vmcnt(0) above
      #pragma unroll
      for (int r = 0; r < 4; ++r) xw_cur[j][r] = bf2f((u16)xwraw[j][r]);
    }

    // protect hbuf from next round's overwrite until all waves consumed it
    __syncthreads();
  }
}

// ---------- launch ----------
extern "C" void kernel_launch(void* const* d_in, const int* in_sizes, int n_in,
                              void* d_out, int out_size, void* d_ws, size_t ws_size,
                              hipStream_t stream) {
  const float* x    = (const float*)d_in[0];
  const float* h0   = (const float*)d_in[1];
  const float* Wih  = (const float*)d_in[2];
  const float* b_ih = (const float*)d_in[3];
  const float* Wio  = (const float*)d_in[4];
  const float* b_io = (const float*)d_in[5];
  float* out = (float*)d_out;

  char* ws = (char*)d_ws;
  u16* Aall = (u16*)(ws);                        // 402,653,184 B
  u16* XW   = (u16*)(ws + 402653184L);           // 268,435,456 B
  u16* Wx   = (u16*)(ws + 671088640L);           //   1,048,576 B
  u16* Wh   = (u16*)(ws + 672137216L);           //   2,097,152 B
  u16* WioB = (u16*)(ws + 674234368L);           //   1,572,864 B
  unsigned* flags = (unsigned*)(ws + 675807232L);//       2,048 B (512 u32)

  // prep
  k_prep_x<<<2048, 256, 0, stream>>>(x, Aall);
  k_prep_w<<<512, 256, 0, stream>>>(Wih, Wio, Wx, Wh, WioB);
  k_prep_h0<<<64, 256, 0, stream>>>(h0, Aall, flags);

  // phase 1: XW = x @ Wih_x^T   (M=R_, N=H_=1024, K=I_)
  k_gemm<I_, KC_, H_, true, false>
      <<<dim3(R_/64, H_/256), 256, 0, stream>>>(Aall, Wx, (void*)XW, nullptr);

  // phase 2: persistent recurrence (64 wgs, 64KB static LDS, Wh in VGPRs)
  k_rnn<<<64, 256, 0, stream>>>(Aall, Wh, XW, b_ih, out + (long)R_ * O_, flags);

  // phase 3: outputs = Aall @ Wio^T + b_io  (M=R_, N=O_=512, K=KC_)
  k_gemm<KC_, KC_, O_, false, true>
      <<<dim3(R_/64, O_/256), 256, 0, stream>>>(Aall, WioB, d_out, b_io);
}